// Round 4
// baseline (270.935 us; speedup 1.0000x reference)
//
#include <hip/hip_runtime.h>

// Non-local (SAGAN) block on MI355X. B=8, C=256, C'=64, N=4096.
// Round 4: flash rewritten on mfma_f32_32x32x16_bf16 (halves LDS frag reads +
// MFMA instr count), Q frags from global, P tile stored bf16 via DPP pair-pack.
// ws: qT[b][n][c'] bf16 4MB | kT 4MB | vB[b][c'][n] 4MB | sa[b][n][c'] f32 8MB | Wb bf16 128KB

#define Bsz 8
#define Cch 256
#define CPd 64
#define Nn  4096
#define TIL 64

typedef __attribute__((ext_vector_type(8)))  short short8;   // 8 bf16 (MFMA A/B frag)
typedef __attribute__((ext_vector_type(4)))  float f32x4;    // 16x16 C/D frag
typedef __attribute__((ext_vector_type(16))) float f32x16;   // 32x32 C/D frag

static constexpr float C1 = (float)(1.41421 / 16.0);  // ROOT_2/sqrt(C)
static constexpr float C2 = (float)(1.41421 / 8.0);   // ROOT_2/sqrt(C')

__device__ inline unsigned pk_trunc(float lo, float hi) { // -> bf16x2 (truncate), 1 v_perm
    return __builtin_amdgcn_perm(__float_as_uint(hi), __float_as_uint(lo), 0x07060302u);
}
__device__ inline float dpp_swap1(float v) {  // lane l <-> l^1 (quad_perm [1,0,3,2])
    return __uint_as_float((unsigned)__builtin_amdgcn_mov_dpp(
        (int)__float_as_uint(v), 0xB1, 0xF, 0xF, true));
}

// -------------------------------------------------------- W f32->bf16 conv --
__global__ __launch_bounds__(256) void wconv_kernel(
    const float* __restrict__ Wq, const float* __restrict__ Wk,
    const float* __restrict__ Wv, const float* __restrict__ Wo,
    unsigned short* __restrict__ Wb)
{
    const int idx = (blockIdx.x * 256 + threadIdx.x) * 4;   // grid 64 -> 65536 elements
    const float* src = (idx < 16384) ? Wq : (idx < 32768) ? Wk : (idx < 49152) ? Wv : Wo;
    const float4 v = *(const float4*)(src + (idx & 16383));
    *(uint2*)(Wb + idx) = make_uint2(pk_trunc(v.x, v.y), pk_trunc(v.z, v.w));
}

// --------------------------------------------------------- QKV proj (MFMA) --
// (round-3 version, unchanged)
__global__ __launch_bounds__(256) void qkv_kernel(
    const float* __restrict__ x, const unsigned short* __restrict__ Wb,
    const float* __restrict__ bq, const float* __restrict__ bk, const float* __restrict__ bv,
    unsigned short* __restrict__ qT, unsigned short* __restrict__ kT,
    unsigned short* __restrict__ vB)
{
    __shared__ __align__(16) float T[TIL * 68];

    const int b   = blockIdx.y;
    const int n0  = blockIdx.x * TIL;
    const int t   = threadIdx.x;
    const int g   = t >> 6;
    const int l15 = t & 15;
    const int l4  = (t & 63) >> 4;

    const float* xb = x + (size_t)b * Cch * Nn + n0 + 16 * g + l15;
    short8 xf[8];
    #pragma unroll
    for (int ks = 0; ks < 8; ++ks) {
        float xr[8];
        #pragma unroll
        for (int j = 0; j < 8; ++j)
            xr[j] = C1 * xb[(size_t)(8 * l4 + 32 * ks + j) * Nn];
        union { unsigned u[4]; short8 s; } p;
        p.u[0] = pk_trunc(xr[0], xr[1]); p.u[1] = pk_trunc(xr[2], xr[3]);
        p.u[2] = pk_trunc(xr[4], xr[5]); p.u[3] = pk_trunc(xr[6], xr[7]);
        xf[ks] = p.s;
    }

    #pragma unroll
    for (int mat = 0; mat < 3; ++mat) {
        const unsigned short* W = Wb + mat * 16384;          // [o=64][c=256] bf16
        const float* bias = (mat == 0) ? bq : (mat == 1) ? bk : bv;

        f32x4 acc[4];
        #pragma unroll
        for (int st = 0; st < 4; ++st) {
            const float bb = bias[16 * st + l15];
            acc[st] = (f32x4){bb, bb, bb, bb};
        }
        #pragma unroll
        for (int st = 0; st < 4; ++st) {
            #pragma unroll
            for (int ks = 0; ks < 8; ++ks) {
                const short8 wf = *(const short8*)&W[(16 * st + l15) * Cch + 8 * l4 + 32 * ks];
                acc[st] = __builtin_amdgcn_mfma_f32_16x16x32_bf16(xf[ks], wf, acc[st], 0, 0, 0);
            }
        }

        __syncthreads();
        if (mat < 2) {
            #pragma unroll
            for (int st = 0; st < 4; ++st)
                #pragma unroll
                for (int r = 0; r < 4; ++r)
                    T[(16 * g + 4 * l4 + r) * 68 + 16 * st + l15] = acc[st][r];
        } else {
            #pragma unroll
            for (int st = 0; st < 4; ++st)
                #pragma unroll
                for (int r = 0; r < 4; ++r)
                    T[(16 * st + l15) * 68 + 16 * g + 4 * l4 + r] = acc[st][r];
        }
        __syncthreads();

        const int row = t >> 2;
        const int sg  = 16 * (t & 3);
        const float4 a0 = *(const float4*)&T[row * 68 + sg + 0];
        const float4 a1 = *(const float4*)&T[row * 68 + sg + 4];
        const float4 a2 = *(const float4*)&T[row * 68 + sg + 8];
        const float4 a3 = *(const float4*)&T[row * 68 + sg + 12];
        const uint4 lo = make_uint4(pk_trunc(a0.x, a0.y), pk_trunc(a0.z, a0.w),
                                    pk_trunc(a1.x, a1.y), pk_trunc(a1.z, a1.w));
        const uint4 hi = make_uint4(pk_trunc(a2.x, a2.y), pk_trunc(a2.z, a2.w),
                                    pk_trunc(a3.x, a3.y), pk_trunc(a3.z, a3.w));
        unsigned short* dst;
        if (mat < 2) {
            dst = (mat == 0 ? qT : kT) + ((size_t)(b * Nn + n0 + row)) * CPd + sg;
        } else {
            dst = vB + ((size_t)(b * CPd + row)) * Nn + n0 + sg;
        }
        *(uint4*)dst = lo;
        *(uint4*)(dst + 8) = hi;
    }
}

// ------------------------------------------------------ flash (32x32 MFMA) --
// Block = (b, 64 q-rows). Waves: nh = w&1 (row half), mq = w>>1 (m half for S,
// c half for PV). S^: D[n][m] 32x32; P packed bf16 -> Pb; PV: D[n][c] 32x32.
// 32x32x16 layouts: A/B lane l: [row=l&31][k=8*(l>>5)+j]; C/D lane l:
// [row=(r&3)+8*(r>>2)+4*(l>>5)][col=l&31]  (HW-verified m74/m101).
__global__ __launch_bounds__(256, 4) void flash_kernel(
    const unsigned short* __restrict__ qT, const unsigned short* __restrict__ kT,
    const unsigned short* __restrict__ vB, float* __restrict__ sa_t)
{
    __shared__ __align__(16) unsigned short Ks[TIL * 72];  // [m][c], stride 72 shorts
    __shared__ __align__(16) unsigned short Vs[TIL * 72];  // [c][m]
    __shared__ __align__(16) unsigned Pb[TIL * 40];        // bf16-pair [n][m/2], stride 40 u32
    __shared__ float Lsh[TIL];

    const int b   = blockIdx.y;
    const int n0  = blockIdx.x * TIL;
    const int t   = threadIdx.x;
    const int l   = t & 63;
    const int w   = t >> 6;
    const int nh  = w & 1;
    const int mq  = w >> 1;
    const int l31 = l & 31;
    const int l1  = l >> 5;

    if (t < TIL) Lsh[t] = 0.f;

    // Q A-frags straight from global: row n = n0+32nh+l31, k-step kc: c = 16kc+8*l1+j
    short8 qf[4];
    {
        const unsigned short* qp = qT + (size_t)(b * Nn + n0 + 32 * nh + l31) * CPd + 8 * l1;
        #pragma unroll
        for (int kc = 0; kc < 4; ++kc) qf[kc] = *(const short8*)(qp + 16 * kc);
    }

    f32x16 acco;
    float Lp[16];
    #pragma unroll
    for (int r = 0; r < 16; ++r) { acco[r] = 0.f; Lp[r] = 0.f; }

    const uint4* kg = (const uint4*)(kT + (size_t)b * Nn * CPd);
    const unsigned short* vb = vB + (size_t)b * CPd * Nn;
    const unsigned sel = (l & 1) ? 0x03020706u : 0x07060302u;   // parity-swapped pack selector
    const int par  = l & 1;
    const int colp = 16 * mq + (l31 >> 1);

    for (int m0 = 0; m0 < Nn; m0 += TIL) {
        __syncthreads();   // prior PV reads of Ks/Vs/Pb done
        {   // stage K [m][c] and V [c][m]; lanes 0-7 = one row -> conflict-free phases
            const int r = t >> 3, cc = t & 7;
            uint4 k0 = kg[(m0 + r) * 8 + cc];
            uint4 k1 = kg[(m0 + r + 32) * 8 + cc];
            *(uint4*)&Ks[r * 72 + 8 * cc]        = k0;
            *(uint4*)&Ks[(r + 32) * 72 + 8 * cc] = k1;
            uint4 w0 = *(const uint4*)(vb + (size_t)r * Nn + m0 + 8 * cc);
            uint4 w1 = *(const uint4*)(vb + (size_t)(r + 32) * Nn + m0 + 8 * cc);
            *(uint4*)&Vs[r * 72 + 8 * cc]        = w0;
            *(uint4*)&Vs[(r + 32) * 72 + 8 * cc] = w1;
        }
        __syncthreads();

        // ---- S subtile [32n x 32m]: 4 k-steps over c ----
        f32x16 accs;
        #pragma unroll
        for (int r = 0; r < 16; ++r) accs[r] = 0.f;
        #pragma unroll
        for (int kc = 0; kc < 4; ++kc) {
            const short8 kf = *(const short8*)&Ks[(32 * mq + l31) * 72 + 16 * kc + 8 * l1];
            accs = __builtin_amdgcn_mfma_f32_32x32x16_bf16(qf[kc], kf, accs, 0, 0, 0);
        }

        // ---- P = exp(S); pack m-pairs across lane pairs (DPP); write to Pb ----
        unsigned u[16];
        #pragma unroll
        for (int r = 0; r < 16; ++r) {
            float p = __expf(accs[r]);
            Lp[r] += p;
            float nb = dpp_swap1(p);
            u[r] = __builtin_amdgcn_perm(__float_as_uint(nb), __float_as_uint(p), sel);
        }
        {   // even lane writes rows (0,1) of each quad, odd rows (2,3): no duplication
            const int rb = 32 * nh + 4 * l1 + 2 * par;
            #pragma unroll
            for (int q = 0; q < 4; ++q) {
                Pb[(rb + 8 * q) * 40 + colp]     = u[4 * q + 2 * par];
                Pb[(rb + 8 * q + 1) * 40 + colp] = u[4 * q + 2 * par + 1];
            }
        }
        __syncthreads();   // P visible

        // ---- O subtile [32n x 32c] += P V^T: 4 k-steps over m ----
        #pragma unroll
        for (int ks = 0; ks < 4; ++ks) {
            const short8 pf = *(const short8*)&Pb[(32 * nh + l31) * 40 + 8 * ks + 4 * l1];
            const short8 vf = *(const short8*)&Vs[(32 * mq + l31) * 72 + 16 * ks + 8 * l1];
            acco = __builtin_amdgcn_mfma_f32_32x32x16_bf16(pf, vf, acco, 0, 0, 0);
        }
    }

    // row-sum reduction: 32 lanes (l31) x 2 waves (mq) contribute per row
    #pragma unroll
    for (int r = 0; r < 16; ++r)
        atomicAdd(&Lsh[32 * nh + (r & 3) + 8 * (r >> 2) + 4 * l1], Lp[r]);
    __syncthreads();

    float* sab = sa_t + (size_t)(b * Nn + n0) * CPd;
    #pragma unroll
    for (int r = 0; r < 16; ++r) {
        const int nl = 32 * nh + (r & 3) + 8 * (r >> 2) + 4 * l1;
        sab[(size_t)nl * CPd + 32 * mq + l31] = acco[r] * (C2 / Lsh[nl]);
    }
}

// ------------------------------------------------------- output proj (MFMA) --
// (round-3 version, unchanged)
__global__ __launch_bounds__(256) void out_kernel(
    const float* __restrict__ sa_t, const unsigned short* __restrict__ Wob,
    const float* __restrict__ bo, const float* __restrict__ gamma,
    const float* __restrict__ x, float* __restrict__ y)
{
    __shared__ __align__(16) unsigned short Wos[Cch * 72];
    __shared__ __align__(16) unsigned short Sas[TIL * 72];
    __shared__ float bos[Cch];

    const int b   = blockIdx.y;
    const int n0  = blockIdx.x * TIL;
    const int t   = threadIdx.x;
    const int l   = t & 63;
    const int g   = t >> 6;
    const int l15 = l & 15;
    const int l4  = l >> 4;

    bos[t] = bo[t];
    {
        const uint4* wg = (const uint4*)Wob;
        #pragma unroll
        for (int p = 0; p < 8; ++p) {
            const int idx = p * 256 + t;
            const int row = idx >> 3, seg = idx & 7;
            *(uint4*)&Wos[row * 72 + seg * 8] = wg[idx];
        }
        const float* sab = sa_t + (size_t)(b * Nn + n0) * CPd;
        const int n = t >> 2, seg = t & 3;
        const float4* sr = (const float4*)(sab + (size_t)n * CPd + seg * 16);
        float4 s0 = sr[0], s1 = sr[1], s2 = sr[2], s3 = sr[3];
        *(uint4*)&Sas[n * 72 + seg * 16] =
            make_uint4(pk_trunc(s0.x, s0.y), pk_trunc(s0.z, s0.w),
                       pk_trunc(s1.x, s1.y), pk_trunc(s1.z, s1.w));
        *(uint4*)&Sas[n * 72 + seg * 16 + 8] =
            make_uint4(pk_trunc(s2.x, s2.y), pk_trunc(s2.z, s2.w),
                       pk_trunc(s3.x, s3.y), pk_trunc(s3.z, s3.w));
    }
    __syncthreads();

    short8 bfr[4][2];
    #pragma unroll
    for (int ns = 0; ns < 4; ++ns) {
        bfr[ns][0] = *(const short8*)&Sas[(16 * ns + l15) * 72 + 8 * l4];
        bfr[ns][1] = *(const short8*)&Sas[(16 * ns + l15) * 72 + 8 * l4 + 32];
    }
    const float gam = gamma[0];
    const float* xb = x + (size_t)b * Cch * Nn;
    float*       yb = y + (size_t)b * Cch * Nn;

    #pragma unroll
    for (int os = 0; os < 4; ++os) {
        const int obase = 64 * g + 16 * os;
        const short8 af0 = *(const short8*)&Wos[(obase + l15) * 72 + 8 * l4];
        const short8 af1 = *(const short8*)&Wos[(obase + l15) * 72 + 8 * l4 + 32];
        #pragma unroll
        for (int ns = 0; ns < 4; ++ns) {
            f32x4 acc = (f32x4){0.f, 0.f, 0.f, 0.f};
            acc = __builtin_amdgcn_mfma_f32_16x16x32_bf16(af0, bfr[ns][0], acc, 0, 0, 0);
            acc = __builtin_amdgcn_mfma_f32_16x16x32_bf16(af1, bfr[ns][1], acc, 0, 0, 0);
            #pragma unroll
            for (int r = 0; r < 4; ++r) {
                const int o = obase + 4 * l4 + r;
                const size_t idx = (size_t)o * Nn + n0 + 16 * ns + l15;
                yb[idx] = fmaf(gam, acc[r] + bos[o], xb[idx]);
            }
        }
    }
}

// ---------------------------------------------------------------------------
extern "C" void kernel_launch(void* const* d_in, const int* in_sizes, int n_in,
                              void* d_out, int out_size, void* d_ws, size_t ws_size,
                              hipStream_t stream)
{
    (void)in_sizes; (void)n_in; (void)out_size; (void)ws_size;
    const float* x     = (const float*)d_in[0];
    const float* Wq    = (const float*)d_in[1];
    const float* bq    = (const float*)d_in[2];
    const float* Wk    = (const float*)d_in[3];
    const float* bk    = (const float*)d_in[4];
    const float* Wv    = (const float*)d_in[5];
    const float* bv    = (const float*)d_in[6];
    const float* Wo    = (const float*)d_in[7];
    const float* bo    = (const float*)d_in[8];
    const float* gamma = (const float*)d_in[9];
    float* y = (float*)d_out;

    const size_t per = (size_t)Bsz * Nn * CPd;           // 2M elements
    unsigned short* qT = (unsigned short*)d_ws;          // 4 MB
    unsigned short* kT = qT + per;                       // 4 MB
    unsigned short* vB = kT + per;                       // 4 MB
    float* sa = (float*)(vB + per);                      // 8 MB
    unsigned short* Wb = (unsigned short*)(sa + per);    // 128 KB: [Wq|Wk|Wv|Wo] bf16

    dim3 grid(Nn / TIL, Bsz);
    wconv_kernel<<<64, 256, 0, stream>>>(Wq, Wk, Wv, Wo, Wb);
    qkv_kernel<<<grid, 256, 0, stream>>>(x, Wb, bq, bk, bv, qT, kT, vB);
    flash_kernel<<<grid, 256, 0, stream>>>(qT, kT, vB, sa);
    out_kernel<<<grid, 256, 0, stream>>>(sa, Wb + 3 * 16384, bo, gamma, x, y);
}

// Round 5
// 211.628 us; speedup vs baseline: 1.2802x; 1.2802x over previous
//
#include <hip/hip_runtime.h>

// Non-local (SAGAN) block on MI355X. B=8, C=256, C'=64, N=4096.
// Round 5: flash = round-3 16x16 structure (4-way MFMA ILP) + 2-way KV split
// (linear partial combine, no online max needed) + Q-frags from global.
// out_kernel combines partials: sa = C2*(O0+O1)/(L0+L1).
// ws: qT 4MB | kT 4MB | vB 4MB | Op[2][b][n][c'] f32 16MB | Lg[2][b][n] 256KB | Wb 128KB

#define Bsz 8
#define Cch 256
#define CPd 64
#define Nn  4096
#define TIL 64
#define NSPL 2                 // KV split factor
#define MHALF (Nn / NSPL)      // 2048

typedef __attribute__((ext_vector_type(8))) short short8;   // 8 bf16 (MFMA A/B frag)
typedef __attribute__((ext_vector_type(4))) float f32x4;    // 16x16 C/D frag

static constexpr float C1 = (float)(1.41421 / 16.0);  // ROOT_2/sqrt(C)
static constexpr float C2 = (float)(1.41421 / 8.0);   // ROOT_2/sqrt(C')

__device__ inline unsigned pk_trunc(float lo, float hi) { // -> bf16x2 (truncate), 1 v_perm
    return __builtin_amdgcn_perm(__float_as_uint(hi), __float_as_uint(lo), 0x07060302u);
}

// -------------------------------------------------------- W f32->bf16 conv --
__global__ __launch_bounds__(256) void wconv_kernel(
    const float* __restrict__ Wq, const float* __restrict__ Wk,
    const float* __restrict__ Wv, const float* __restrict__ Wo,
    unsigned short* __restrict__ Wb)
{
    const int idx = (blockIdx.x * 256 + threadIdx.x) * 4;   // grid 64 -> 65536 elements
    const float* src = (idx < 16384) ? Wq : (idx < 32768) ? Wk : (idx < 49152) ? Wv : Wo;
    const float4 v = *(const float4*)(src + (idx & 16383));
    *(uint2*)(Wb + idx) = make_uint2(pk_trunc(v.x, v.y), pk_trunc(v.z, v.w));
}

// --------------------------------------------------------- QKV proj (MFMA) --
// (round-3 version, unchanged — proven)
__global__ __launch_bounds__(256) void qkv_kernel(
    const float* __restrict__ x, const unsigned short* __restrict__ Wb,
    const float* __restrict__ bq, const float* __restrict__ bk, const float* __restrict__ bv,
    unsigned short* __restrict__ qT, unsigned short* __restrict__ kT,
    unsigned short* __restrict__ vB)
{
    __shared__ __align__(16) float T[TIL * 68];

    const int b   = blockIdx.y;
    const int n0  = blockIdx.x * TIL;
    const int t   = threadIdx.x;
    const int g   = t >> 6;
    const int l15 = t & 15;
    const int l4  = (t & 63) >> 4;

    const float* xb = x + (size_t)b * Cch * Nn + n0 + 16 * g + l15;
    short8 xf[8];
    #pragma unroll
    for (int ks = 0; ks < 8; ++ks) {
        float xr[8];
        #pragma unroll
        for (int j = 0; j < 8; ++j)
            xr[j] = C1 * xb[(size_t)(8 * l4 + 32 * ks + j) * Nn];
        union { unsigned u[4]; short8 s; } p;
        p.u[0] = pk_trunc(xr[0], xr[1]); p.u[1] = pk_trunc(xr[2], xr[3]);
        p.u[2] = pk_trunc(xr[4], xr[5]); p.u[3] = pk_trunc(xr[6], xr[7]);
        xf[ks] = p.s;
    }

    #pragma unroll
    for (int mat = 0; mat < 3; ++mat) {
        const unsigned short* W = Wb + mat * 16384;          // [o=64][c=256] bf16
        const float* bias = (mat == 0) ? bq : (mat == 1) ? bk : bv;

        f32x4 acc[4];
        #pragma unroll
        for (int st = 0; st < 4; ++st) {
            const float bb = bias[16 * st + l15];
            acc[st] = (f32x4){bb, bb, bb, bb};
        }
        #pragma unroll
        for (int st = 0; st < 4; ++st) {
            #pragma unroll
            for (int ks = 0; ks < 8; ++ks) {
                const short8 wf = *(const short8*)&W[(16 * st + l15) * Cch + 8 * l4 + 32 * ks];
                acc[st] = __builtin_amdgcn_mfma_f32_16x16x32_bf16(xf[ks], wf, acc[st], 0, 0, 0);
            }
        }

        __syncthreads();
        if (mat < 2) {
            #pragma unroll
            for (int st = 0; st < 4; ++st)
                #pragma unroll
                for (int r = 0; r < 4; ++r)
                    T[(16 * g + 4 * l4 + r) * 68 + 16 * st + l15] = acc[st][r];
        } else {
            #pragma unroll
            for (int st = 0; st < 4; ++st)
                #pragma unroll
                for (int r = 0; r < 4; ++r)
                    T[(16 * st + l15) * 68 + 16 * g + 4 * l4 + r] = acc[st][r];
        }
        __syncthreads();

        const int row = t >> 2;
        const int sg  = 16 * (t & 3);
        const float4 a0 = *(const float4*)&T[row * 68 + sg + 0];
        const float4 a1 = *(const float4*)&T[row * 68 + sg + 4];
        const float4 a2 = *(const float4*)&T[row * 68 + sg + 8];
        const float4 a3 = *(const float4*)&T[row * 68 + sg + 12];
        const uint4 lo = make_uint4(pk_trunc(a0.x, a0.y), pk_trunc(a0.z, a0.w),
                                    pk_trunc(a1.x, a1.y), pk_trunc(a1.z, a1.w));
        const uint4 hi = make_uint4(pk_trunc(a2.x, a2.y), pk_trunc(a2.z, a2.w),
                                    pk_trunc(a3.x, a3.y), pk_trunc(a3.z, a3.w));
        unsigned short* dst;
        if (mat < 2) {
            dst = (mat == 0 ? qT : kT) + ((size_t)(b * Nn + n0 + row)) * CPd + sg;
        } else {
            dst = vB + ((size_t)(b * CPd + row)) * Nn + n0 + sg;
        }
        *(uint4*)dst = lo;
        *(uint4*)(dst + 8) = hi;
    }
}

// ------------------------------------------------------------ flash (MFMA) --
// Block = (b, 64 q-rows, KV slice s). Writes UNNORMALIZED O partial + L partial.
// Wave g owns n-strip [16g,16g+16). 16x16x32 MFMA, 4 independent acc chains.
__global__ __launch_bounds__(256, 4) void flash_kernel(
    const unsigned short* __restrict__ qT, const unsigned short* __restrict__ kT,
    const unsigned short* __restrict__ vB, float* __restrict__ Op, float* __restrict__ Lg)
{
    __shared__ __align__(16) unsigned short Ks[TIL * 72];  // [m][c]
    __shared__ __align__(16) unsigned short Vs[TIL * 72];  // [c][m]
    __shared__ __align__(16) float Ps[TIL * 68];           // [n][m] f32
    __shared__ float Lsh[TIL];

    const int b   = blockIdx.y;
    const int n0  = blockIdx.x * TIL;
    const int s   = blockIdx.z;
    const int t   = threadIdx.x;
    const int l   = t & 63;
    const int g   = t >> 6;
    const int l15 = l & 15;
    const int l4  = l >> 4;

    if (t < TIL) Lsh[t] = 0.f;

    // Q A-frags straight from global: row n = n0+16g+l15, k: c = 8*l4+j (+32)
    const unsigned short* qp = qT + (size_t)(b * Nn + n0 + 16 * g + l15) * CPd + 8 * l4;
    const short8 qf0 = *(const short8*)qp;
    const short8 qf1 = *(const short8*)(qp + 32);

    f32x4 acco[4];
    #pragma unroll
    for (int ct = 0; ct < 4; ++ct) acco[ct] = (f32x4){0.f, 0.f, 0.f, 0.f};
    float Lp[4] = {0.f, 0.f, 0.f, 0.f};

    const uint4* kg = (const uint4*)(kT + (size_t)b * Nn * CPd);
    const unsigned short* vb = vB + (size_t)b * CPd * Nn;
    const int mbase = s * MHALF;

    for (int mi = 0; mi < MHALF; mi += TIL) {
        const int m0 = mbase + mi;
        __syncthreads();   // prior PV reads of Ks/Vs done (and Lsh init on iter 0)
        {   // stage K [m][c] and V [c][m]
            const int r = t >> 3, cc = t & 7;
            uint4 k0 = kg[(m0 + r) * 8 + cc];
            uint4 k1 = kg[(m0 + r + 32) * 8 + cc];
            *(uint4*)&Ks[r * 72 + 8 * cc]        = k0;
            *(uint4*)&Ks[(r + 32) * 72 + 8 * cc] = k1;
            uint4 w0 = *(const uint4*)(vb + (size_t)r * Nn + m0 + 8 * cc);
            uint4 w1 = *(const uint4*)(vb + (size_t)(r + 32) * Nn + m0 + 8 * cc);
            *(uint4*)&Vs[r * 72 + 8 * cc]        = w0;
            *(uint4*)&Vs[(r + 32) * 72 + 8 * cc] = w1;
        }
        __syncthreads();

        // ---- S = Q^T K: 4 independent col-subtile chains x 2 k-steps ----
        f32x4 accs[4];
        #pragma unroll
        for (int st = 0; st < 4; ++st) {
            accs[st] = (f32x4){0.f, 0.f, 0.f, 0.f};
            const short8 kf0 = *(const short8*)&Ks[(16 * st + l15) * 72 + 8 * l4];
            const short8 kf1 = *(const short8*)&Ks[(16 * st + l15) * 72 + 8 * l4 + 32];
            accs[st] = __builtin_amdgcn_mfma_f32_16x16x32_bf16(qf0, kf0, accs[st], 0, 0, 0);
            accs[st] = __builtin_amdgcn_mfma_f32_16x16x32_bf16(qf1, kf1, accs[st], 0, 0, 0);
        }

        // ---- P = exp(S) -> LDS (C/D layout write: row=16g+4*l4+r, col=16st+l15) ----
        #pragma unroll
        for (int st = 0; st < 4; ++st) {
            #pragma unroll
            for (int r = 0; r < 4; ++r) {
                float p = __expf(accs[st][r]);
                Lp[r] += p;
                Ps[(16 * g + 4 * l4 + r) * 68 + 16 * st + l15] = p;
            }
        }
        __syncthreads();   // P visible

        // ---- O += P V^T: A-frag P[n=16g+l15][m], B-frag V[c=16ct+l15][m] ----
        #pragma unroll
        for (int ks = 0; ks < 2; ++ks) {
            const float4 a0 = *(const float4*)&Ps[(16 * g + l15) * 68 + 8 * l4 + 32 * ks];
            const float4 a1 = *(const float4*)&Ps[(16 * g + l15) * 68 + 8 * l4 + 32 * ks + 4];
            union { unsigned u[4]; short8 s8; } pu;
            pu.u[0] = pk_trunc(a0.x, a0.y); pu.u[1] = pk_trunc(a0.z, a0.w);
            pu.u[2] = pk_trunc(a1.x, a1.y); pu.u[3] = pk_trunc(a1.z, a1.w);
            #pragma unroll
            for (int ct = 0; ct < 4; ++ct) {
                const short8 vf = *(const short8*)&Vs[(16 * ct + l15) * 72 + 8 * l4 + 32 * ks];
                acco[ct] = __builtin_amdgcn_mfma_f32_16x16x32_bf16(pu.s8, vf, acco[ct], 0, 0, 0);
            }
        }
    }

    // partial row-sums: 16 l15-lanes contribute to row 16g+4*l4+r
    #pragma unroll
    for (int r = 0; r < 4; ++r) atomicAdd(&Lsh[16 * g + 4 * l4 + r], Lp[r]);
    __syncthreads();

    // unnormalized O partial out (slice-major)
    float* ob = Op + ((size_t)(s * Bsz + b) * Nn + n0) * CPd;
    #pragma unroll
    for (int r = 0; r < 4; ++r) {
        const int nl = 16 * g + 4 * l4 + r;
        #pragma unroll
        for (int ct = 0; ct < 4; ++ct)
            ob[(size_t)nl * CPd + 16 * ct + l15] = acco[ct][r];
    }
    if (t < TIL) Lg[(size_t)(s * Bsz + b) * Nn + n0 + t] = Lsh[t];
}

// ------------------------------------------------------- output proj (MFMA) --
// Combines KV-split partials during staging: sa = C2*(O0+O1)/(L0+L1), then
// out[o][n] = Wo @ sa;  y = gamma*(out+bo) + x
__global__ __launch_bounds__(256) void out_kernel(
    const float* __restrict__ Op, const float* __restrict__ Lg,
    const unsigned short* __restrict__ Wob,
    const float* __restrict__ bo, const float* __restrict__ gamma,
    const float* __restrict__ x, float* __restrict__ y)
{
    __shared__ __align__(16) unsigned short Wos[Cch * 72];
    __shared__ __align__(16) unsigned short Sas[TIL * 72];
    __shared__ float bos[Cch];

    const int b   = blockIdx.y;
    const int n0  = blockIdx.x * TIL;
    const int t   = threadIdx.x;
    const int l   = t & 63;
    const int g   = t >> 6;
    const int l15 = l & 15;
    const int l4  = l >> 4;

    bos[t] = bo[t];
    {
        const uint4* wg = (const uint4*)Wob;
        #pragma unroll
        for (int p = 0; p < 8; ++p) {
            const int idx = p * 256 + t;
            const int row = idx >> 3, seg = idx & 7;
            *(uint4*)&Wos[row * 72 + seg * 8] = wg[idx];
        }
        const int n = t >> 2, seg = t & 3;
        const float* o0 = Op + ((size_t)(b * Nn + n0 + n)) * CPd + seg * 16;
        const float* o1 = o0 + (size_t)Bsz * Nn * CPd;
        const float l0 = Lg[(size_t)b * Nn + n0 + n];
        const float l1 = Lg[(size_t)(Bsz + b) * Nn + n0 + n];
        const float sc = C2 / (l0 + l1);
        unsigned pk[8];
        #pragma unroll
        for (int i = 0; i < 4; ++i) {
            const float4 a = ((const float4*)o0)[i];
            const float4 c = ((const float4*)o1)[i];
            pk[2 * i]     = pk_trunc((a.x + c.x) * sc, (a.y + c.y) * sc);
            pk[2 * i + 1] = pk_trunc((a.z + c.z) * sc, (a.w + c.w) * sc);
        }
        *(uint4*)&Sas[n * 72 + seg * 16]     = make_uint4(pk[0], pk[1], pk[2], pk[3]);
        *(uint4*)&Sas[n * 72 + seg * 16 + 8] = make_uint4(pk[4], pk[5], pk[6], pk[7]);
    }
    __syncthreads();

    short8 bfr[4][2];
    #pragma unroll
    for (int ns = 0; ns < 4; ++ns) {
        bfr[ns][0] = *(const short8*)&Sas[(16 * ns + l15) * 72 + 8 * l4];
        bfr[ns][1] = *(const short8*)&Sas[(16 * ns + l15) * 72 + 8 * l4 + 32];
    }
    const float gam = gamma[0];
    const float* xb = x + (size_t)b * Cch * Nn;
    float*       yb = y + (size_t)b * Cch * Nn;

    #pragma unroll
    for (int os = 0; os < 4; ++os) {
        const int obase = 64 * g + 16 * os;
        const short8 af0 = *(const short8*)&Wos[(obase + l15) * 72 + 8 * l4];
        const short8 af1 = *(const short8*)&Wos[(obase + l15) * 72 + 8 * l4 + 32];
        #pragma unroll
        for (int ns = 0; ns < 4; ++ns) {
            f32x4 acc = (f32x4){0.f, 0.f, 0.f, 0.f};
            acc = __builtin_amdgcn_mfma_f32_16x16x32_bf16(af0, bfr[ns][0], acc, 0, 0, 0);
            acc = __builtin_amdgcn_mfma_f32_16x16x32_bf16(af1, bfr[ns][1], acc, 0, 0, 0);
            #pragma unroll
            for (int r = 0; r < 4; ++r) {
                const int o = obase + 4 * l4 + r;
                const size_t idx = (size_t)o * Nn + n0 + 16 * ns + l15;
                yb[idx] = fmaf(gam, acc[r] + bos[o], xb[idx]);
            }
        }
    }
}

// ---------------------------------------------------------------------------
extern "C" void kernel_launch(void* const* d_in, const int* in_sizes, int n_in,
                              void* d_out, int out_size, void* d_ws, size_t ws_size,
                              hipStream_t stream)
{
    (void)in_sizes; (void)n_in; (void)out_size; (void)ws_size;
    const float* x     = (const float*)d_in[0];
    const float* Wq    = (const float*)d_in[1];
    const float* bq    = (const float*)d_in[2];
    const float* Wk    = (const float*)d_in[3];
    const float* bk    = (const float*)d_in[4];
    const float* Wv    = (const float*)d_in[5];
    const float* bv    = (const float*)d_in[6];
    const float* Wo    = (const float*)d_in[7];
    const float* bo    = (const float*)d_in[8];
    const float* gamma = (const float*)d_in[9];
    float* y = (float*)d_out;

    const size_t per = (size_t)Bsz * Nn * CPd;           // 2,097,152 elements
    unsigned short* qT = (unsigned short*)d_ws;          // 4 MB
    unsigned short* kT = qT + per;                       // 4 MB
    unsigned short* vB = kT + per;                       // 4 MB
    float* Op = (float*)(vB + per);                      // 16 MB: [2][b][n][c'] f32
    float* Lg = Op + NSPL * per;                         // 256 KB: [2][b][n] f32
    unsigned short* Wb = (unsigned short*)(Lg + NSPL * Bsz * Nn);  // 128 KB

    dim3 grid(Nn / TIL, Bsz);
    dim3 gridF(Nn / TIL, Bsz, NSPL);
    wconv_kernel<<<64, 256, 0, stream>>>(Wq, Wk, Wv, Wo, Wb);
    qkv_kernel<<<grid, 256, 0, stream>>>(x, Wb, bq, bk, bv, qT, kT, vB);
    flash_kernel<<<gridF, 256, 0, stream>>>(qT, kT, vB, Op, Lg);
    out_kernel<<<grid, 256, 0, stream>>>(Op, Lg, Wb + 3 * 16384, bo, gamma, x, y);
}

// Round 6
// 187.643 us; speedup vs baseline: 1.4439x; 1.1278x over previous
//
#include <hip/hip_runtime.h>

// Non-local (SAGAN) block on MI355X. B=8, C=256, C'=64, N=4096.
// Round 6: flash keeps 16x16/NSPL=2 structure + bf16-P (DPP pair pack);
// qkv stages W in LDS (kills L2-latency MFMA chains); out uses 512 threads.
// ws: qT 4MB | kT 4MB | vB 4MB | Op[2][b][n][c'] f32 16MB | Lg[2][b][n] 256KB | Wb 128KB

#define Bsz 8
#define Cch 256
#define CPd 64
#define Nn  4096
#define TIL 64
#define NSPL 2                 // KV split factor
#define MHALF (Nn / NSPL)      // 2048

typedef __attribute__((ext_vector_type(8))) short short8;   // 8 bf16 (MFMA A/B frag)
typedef __attribute__((ext_vector_type(4))) float f32x4;    // 16x16 C/D frag

static constexpr float C1 = (float)(1.41421 / 16.0);  // ROOT_2/sqrt(C)
static constexpr float C2 = (float)(1.41421 / 8.0);   // ROOT_2/sqrt(C')

__device__ inline unsigned pk_trunc(float lo, float hi) { // -> bf16x2 (truncate), 1 v_perm
    return __builtin_amdgcn_perm(__float_as_uint(hi), __float_as_uint(lo), 0x07060302u);
}
__device__ inline float dpp_swap1(float v) {  // lane l <-> l^1 (quad_perm [1,0,3,2])
    return __uint_as_float((unsigned)__builtin_amdgcn_mov_dpp(
        (int)__float_as_uint(v), 0xB1, 0xF, 0xF, true));
}

// -------------------------------------------------------- W f32->bf16 conv --
__global__ __launch_bounds__(256) void wconv_kernel(
    const float* __restrict__ Wq, const float* __restrict__ Wk,
    const float* __restrict__ Wv, const float* __restrict__ Wo,
    unsigned short* __restrict__ Wb)
{
    const int idx = (blockIdx.x * 256 + threadIdx.x) * 4;   // grid 64 -> 65536 elements
    const float* src = (idx < 16384) ? Wq : (idx < 32768) ? Wk : (idx < 49152) ? Wv : Wo;
    const float4 v = *(const float4*)(src + (idx & 16383));
    *(uint2*)(Wb + idx) = make_uint2(pk_trunc(v.x, v.y), pk_trunc(v.z, v.w));
}

// --------------------------------------------------------- QKV proj (MFMA) --
// Round 6: W tile staged into LDS per mat (L2-latency chains -> ~120cyc LDS).
__global__ __launch_bounds__(256) void qkv_kernel(
    const float* __restrict__ x, const unsigned short* __restrict__ Wb,
    const float* __restrict__ bq, const float* __restrict__ bk, const float* __restrict__ bv,
    unsigned short* __restrict__ qT, unsigned short* __restrict__ kT,
    unsigned short* __restrict__ vB)
{
    __shared__ __align__(16) unsigned short Wlds[CPd * 264];  // [o][c] bf16, stride 264 (33 KB)
    __shared__ __align__(16) float T[TIL * 68];               // 17.4 KB

    const int b   = blockIdx.y;
    const int n0  = blockIdx.x * TIL;
    const int t   = threadIdx.x;
    const int g   = t >> 6;
    const int l15 = t & 15;
    const int l4  = (t & 63) >> 4;

    // A-frags from global x: lane row n = n0+16g+l15, k = c = 8*l4 + j + 32*ks
    const float* xb = x + (size_t)b * Cch * Nn + n0 + 16 * g + l15;
    short8 xf[8];
    #pragma unroll
    for (int ks = 0; ks < 8; ++ks) {
        float xr[8];
        #pragma unroll
        for (int j = 0; j < 8; ++j)
            xr[j] = C1 * xb[(size_t)(8 * l4 + 32 * ks + j) * Nn];
        union { unsigned u[4]; short8 s; } p;
        p.u[0] = pk_trunc(xr[0], xr[1]); p.u[1] = pk_trunc(xr[2], xr[3]);
        p.u[2] = pk_trunc(xr[4], xr[5]); p.u[3] = pk_trunc(xr[6], xr[7]);
        xf[ks] = p.s;
    }

    #pragma unroll
    for (int mat = 0; mat < 3; ++mat) {
        {   // stage W[64][256] bf16 = 2048 uint4, coalesced, 8 per thread
            const uint4* wg = (const uint4*)(Wb + mat * 16384);
            #pragma unroll
            for (int p = 0; p < 8; ++p) {
                const int idx = p * 256 + t;
                const int o = idx >> 5, cs = idx & 31;
                *(uint4*)&Wlds[o * 264 + cs * 8] = wg[idx];
            }
        }
        __syncthreads();   // W staged (also: prev mat's T reads done before next T write)

        const float* bias = (mat == 0) ? bq : (mat == 1) ? bk : bv;
        f32x4 acc[4];
        #pragma unroll
        for (int st = 0; st < 4; ++st) {
            const float bb = bias[16 * st + l15];
            acc[st] = (f32x4){bb, bb, bb, bb};
        }
        #pragma unroll
        for (int st = 0; st < 4; ++st) {
            #pragma unroll
            for (int ks = 0; ks < 8; ++ks) {
                const short8 wf = *(const short8*)&Wlds[(16 * st + l15) * 264 + 8 * l4 + 32 * ks];
                acc[st] = __builtin_amdgcn_mfma_f32_16x16x32_bf16(xf[ks], wf, acc[st], 0, 0, 0);
            }
        }
        __syncthreads();   // all Wlds reads done (next mat may restage)

        if (mat < 2) {     // T as [n][c']
            #pragma unroll
            for (int st = 0; st < 4; ++st)
                #pragma unroll
                for (int r = 0; r < 4; ++r)
                    T[(16 * g + 4 * l4 + r) * 68 + 16 * st + l15] = acc[st][r];
        } else {           // v: T as [c'][n]
            #pragma unroll
            for (int st = 0; st < 4; ++st)
                #pragma unroll
                for (int r = 0; r < 4; ++r)
                    T[(16 * st + l15) * 68 + 16 * g + 4 * l4 + r] = acc[st][r];
        }
        __syncthreads();

        const int row = t >> 2;            // n (q/k) or c' (v)
        const int sg  = 16 * (t & 3);
        const float4 a0 = *(const float4*)&T[row * 68 + sg + 0];
        const float4 a1 = *(const float4*)&T[row * 68 + sg + 4];
        const float4 a2 = *(const float4*)&T[row * 68 + sg + 8];
        const float4 a3 = *(const float4*)&T[row * 68 + sg + 12];
        const uint4 lo = make_uint4(pk_trunc(a0.x, a0.y), pk_trunc(a0.z, a0.w),
                                    pk_trunc(a1.x, a1.y), pk_trunc(a1.z, a1.w));
        const uint4 hi = make_uint4(pk_trunc(a2.x, a2.y), pk_trunc(a2.z, a2.w),
                                    pk_trunc(a3.x, a3.y), pk_trunc(a3.z, a3.w));
        unsigned short* dst;
        if (mat < 2) {
            dst = (mat == 0 ? qT : kT) + ((size_t)(b * Nn + n0 + row)) * CPd + sg;
        } else {
            dst = vB + ((size_t)(b * CPd + row)) * Nn + n0 + sg;
        }
        *(uint4*)dst = lo;
        *(uint4*)(dst + 8) = hi;
    }
}

// ------------------------------------------------------------ flash (MFMA) --
// 16x16 structure, NSPL=2 split; P stored as bf16 pairs (DPP pair pack):
// P writes 16->8 b32, P reads 4->2 b128, PV perms removed.
__global__ __launch_bounds__(256, 4) void flash_kernel(
    const unsigned short* __restrict__ qT, const unsigned short* __restrict__ kT,
    const unsigned short* __restrict__ vB, float* __restrict__ Op, float* __restrict__ Lg)
{
    __shared__ __align__(16) unsigned short Ks[TIL * 72];  // [m][c]
    __shared__ __align__(16) unsigned short Vs[TIL * 72];  // [c][m]
    __shared__ __align__(16) unsigned Pb[TIL * 36];        // bf16-pair [n][m/2], stride 36 u32
    __shared__ float Lsh[TIL];

    const int b   = blockIdx.y;
    const int n0  = blockIdx.x * TIL;
    const int s   = blockIdx.z;
    const int t   = threadIdx.x;
    const int l   = t & 63;
    const int g   = t >> 6;
    const int l15 = l & 15;
    const int l4  = l >> 4;
    const int par = l & 1;
    const unsigned sel = par ? 0x03020706u : 0x07060302u;
    const int l15h = l15 >> 1;

    if (t < TIL) Lsh[t] = 0.f;

    // Q A-frags straight from global
    const unsigned short* qp = qT + (size_t)(b * Nn + n0 + 16 * g + l15) * CPd + 8 * l4;
    const short8 qf0 = *(const short8*)qp;
    const short8 qf1 = *(const short8*)(qp + 32);

    f32x4 acco[4];
    #pragma unroll
    for (int ct = 0; ct < 4; ++ct) acco[ct] = (f32x4){0.f, 0.f, 0.f, 0.f};
    float Lp[4] = {0.f, 0.f, 0.f, 0.f};

    const uint4* kg = (const uint4*)(kT + (size_t)b * Nn * CPd);
    const unsigned short* vb = vB + (size_t)b * CPd * Nn;
    const int mbase = s * MHALF;

    for (int mi = 0; mi < MHALF; mi += TIL) {
        const int m0 = mbase + mi;
        __syncthreads();
        {   // stage K [m][c] and V [c][m]
            const int r = t >> 3, cc = t & 7;
            uint4 k0 = kg[(m0 + r) * 8 + cc];
            uint4 k1 = kg[(m0 + r + 32) * 8 + cc];
            *(uint4*)&Ks[r * 72 + 8 * cc]        = k0;
            *(uint4*)&Ks[(r + 32) * 72 + 8 * cc] = k1;
            uint4 w0 = *(const uint4*)(vb + (size_t)r * Nn + m0 + 8 * cc);
            uint4 w1 = *(const uint4*)(vb + (size_t)(r + 32) * Nn + m0 + 8 * cc);
            *(uint4*)&Vs[r * 72 + 8 * cc]        = w0;
            *(uint4*)&Vs[(r + 32) * 72 + 8 * cc] = w1;
        }
        __syncthreads();

        // ---- S = Q^T K: 4 independent chains x 2 k-steps ----
        f32x4 accs[4];
        #pragma unroll
        for (int st = 0; st < 4; ++st) {
            accs[st] = (f32x4){0.f, 0.f, 0.f, 0.f};
            const short8 kf0 = *(const short8*)&Ks[(16 * st + l15) * 72 + 8 * l4];
            const short8 kf1 = *(const short8*)&Ks[(16 * st + l15) * 72 + 8 * l4 + 32];
            accs[st] = __builtin_amdgcn_mfma_f32_16x16x32_bf16(qf0, kf0, accs[st], 0, 0, 0);
            accs[st] = __builtin_amdgcn_mfma_f32_16x16x32_bf16(qf1, kf1, accs[st], 0, 0, 0);
        }

        // ---- P = exp(S); DPP pair-pack to bf16; write half the rows per parity ----
        #pragma unroll
        for (int st = 0; st < 4; ++st) {
            unsigned u[4];
            #pragma unroll
            for (int r = 0; r < 4; ++r) {
                float p = __expf(accs[st][r]);
                Lp[r] += p;
                float nb = dpp_swap1(p);
                u[r] = __builtin_amdgcn_perm(__float_as_uint(nb), __float_as_uint(p), sel);
            }
            const int rb = 16 * g + 4 * l4 + 2 * par;   // even lane: rows {0,1}; odd: {2,3}
            Pb[(rb + 0) * 36 + 8 * st + l15h] = u[2 * par];
            Pb[(rb + 1) * 36 + 8 * st + l15h] = u[2 * par + 1];
        }
        __syncthreads();   // P visible

        // ---- O += P V^T: A-frag from Pb (pre-packed bf16), B-frag V ----
        #pragma unroll
        for (int ks = 0; ks < 2; ++ks) {
            const short8 pf = *(const short8*)&Pb[(16 * g + l15) * 36 + 4 * l4 + 16 * ks];
            #pragma unroll
            for (int ct = 0; ct < 4; ++ct) {
                const short8 vf = *(const short8*)&Vs[(16 * ct + l15) * 72 + 8 * l4 + 32 * ks];
                acco[ct] = __builtin_amdgcn_mfma_f32_16x16x32_bf16(pf, vf, acco[ct], 0, 0, 0);
            }
        }
    }

    #pragma unroll
    for (int r = 0; r < 4; ++r) atomicAdd(&Lsh[16 * g + 4 * l4 + r], Lp[r]);
    __syncthreads();

    float* ob = Op + ((size_t)(s * Bsz + b) * Nn + n0) * CPd;
    #pragma unroll
    for (int r = 0; r < 4; ++r) {
        const int nl = 16 * g + 4 * l4 + r;
        #pragma unroll
        for (int ct = 0; ct < 4; ++ct)
            ob[(size_t)nl * CPd + 16 * ct + l15] = acco[ct][r];
    }
    if (t < TIL) Lg[(size_t)(s * Bsz + b) * Nn + n0 + t] = Lsh[t];
}

// ------------------------------------------------------- output proj (MFMA) --
// Round 6: 512 threads (16 waves/CU). Waves split the 16 o-strips.
__global__ __launch_bounds__(512) void out_kernel(
    const float* __restrict__ Op, const float* __restrict__ Lg,
    const unsigned short* __restrict__ Wob,
    const float* __restrict__ bo, const float* __restrict__ gamma,
    const float* __restrict__ x, float* __restrict__ y)
{
    __shared__ __align__(16) unsigned short Wos[Cch * 72];  // 36 KB
    __shared__ __align__(16) unsigned short Sas[TIL * 72];  // 9 KB
    __shared__ float bos[Cch];

    const int b   = blockIdx.y;
    const int n0  = blockIdx.x * TIL;
    const int t   = threadIdx.x;     // 0..511
    const int l   = t & 63;
    const int w   = t >> 6;          // 8 waves
    const int l15 = l & 15;
    const int l4  = l >> 4;

    if (t < Cch) bos[t] = bo[t];
    {   // Wo bf16: 2048 uint4 / 512 threads = 4 each
        const uint4* wg = (const uint4*)Wob;
        #pragma unroll
        for (int p = 0; p < 4; ++p) {
            const int idx = p * 512 + t;
            const int row = idx >> 3, seg = idx & 7;
            *(uint4*)&Wos[row * 72 + seg * 8] = wg[idx];
        }
    }
    if (t < 256) {   // combine partials + pack sa tile to bf16
        const int n = t >> 2, seg = t & 3;
        const float* o0 = Op + ((size_t)(b * Nn + n0 + n)) * CPd + seg * 16;
        const float* o1 = o0 + (size_t)Bsz * Nn * CPd;
        const float l0 = Lg[(size_t)b * Nn + n0 + n];
        const float l1 = Lg[(size_t)(Bsz + b) * Nn + n0 + n];
        const float sc = C2 / (l0 + l1);
        unsigned pk[8];
        #pragma unroll
        for (int i = 0; i < 4; ++i) {
            const float4 a = ((const float4*)o0)[i];
            const float4 c = ((const float4*)o1)[i];
            pk[2 * i]     = pk_trunc((a.x + c.x) * sc, (a.y + c.y) * sc);
            pk[2 * i + 1] = pk_trunc((a.z + c.z) * sc, (a.w + c.w) * sc);
        }
        *(uint4*)&Sas[n * 72 + seg * 16]     = make_uint4(pk[0], pk[1], pk[2], pk[3]);
        *(uint4*)&Sas[n * 72 + seg * 16 + 8] = make_uint4(pk[4], pk[5], pk[6], pk[7]);
    }
    __syncthreads();

    short8 bfr[4][2];
    #pragma unroll
    for (int ns = 0; ns < 4; ++ns) {
        bfr[ns][0] = *(const short8*)&Sas[(16 * ns + l15) * 72 + 8 * l4];
        bfr[ns][1] = *(const short8*)&Sas[(16 * ns + l15) * 72 + 8 * l4 + 32];
    }
    const float gam = gamma[0];
    const float* xb = x + (size_t)b * Cch * Nn;
    float*       yb = y + (size_t)b * Cch * Nn;

    #pragma unroll
    for (int os2 = 0; os2 < 2; ++os2) {
        const int obase = 16 * (w + 8 * os2);     // 16 strips over 8 waves x 2
        const short8 af0 = *(const short8*)&Wos[(obase + l15) * 72 + 8 * l4];
        const short8 af1 = *(const short8*)&Wos[(obase + l15) * 72 + 8 * l4 + 32];
        #pragma unroll
        for (int ns = 0; ns < 4; ++ns) {
            f32x4 acc = (f32x4){0.f, 0.f, 0.f, 0.f};
            acc = __builtin_amdgcn_mfma_f32_16x16x32_bf16(af0, bfr[ns][0], acc, 0, 0, 0);
            acc = __builtin_amdgcn_mfma_f32_16x16x32_bf16(af1, bfr[ns][1], acc, 0, 0, 0);
            #pragma unroll
            for (int r = 0; r < 4; ++r) {
                const int o = obase + 4 * l4 + r;
                const size_t idx = (size_t)o * Nn + n0 + 16 * ns + l15;
                yb[idx] = fmaf(gam, acc[r] + bos[o], xb[idx]);
            }
        }
    }
}

// ---------------------------------------------------------------------------
extern "C" void kernel_launch(void* const* d_in, const int* in_sizes, int n_in,
                              void* d_out, int out_size, void* d_ws, size_t ws_size,
                              hipStream_t stream)
{
    (void)in_sizes; (void)n_in; (void)out_size; (void)ws_size;
    const float* x     = (const float*)d_in[0];
    const float* Wq    = (const float*)d_in[1];
    const float* bq    = (const float*)d_in[2];
    const float* Wk    = (const float*)d_in[3];
    const float* bk    = (const float*)d_in[4];
    const float* Wv    = (const float*)d_in[5];
    const float* bv    = (const float*)d_in[6];
    const float* Wo    = (const float*)d_in[7];
    const float* bo    = (const float*)d_in[8];
    const float* gamma = (const float*)d_in[9];
    float* y = (float*)d_out;

    const size_t per = (size_t)Bsz * Nn * CPd;           // 2,097,152 elements
    unsigned short* qT = (unsigned short*)d_ws;          // 4 MB
    unsigned short* kT = qT + per;                       // 4 MB
    unsigned short* vB = kT + per;                       // 4 MB
    float* Op = (float*)(vB + per);                      // 16 MB: [2][b][n][c'] f32
    float* Lg = Op + NSPL * per;                         // 256 KB: [2][b][n] f32
    unsigned short* Wb = (unsigned short*)(Lg + NSPL * Bsz * Nn);  // 128 KB

    dim3 grid(Nn / TIL, Bsz);
    dim3 gridF(Nn / TIL, Bsz, NSPL);
    wconv_kernel<<<64, 256, 0, stream>>>(Wq, Wk, Wv, Wo, Wb);
    qkv_kernel<<<grid, 256, 0, stream>>>(x, Wb, bq, bk, bv, qT, kT, vB);
    flash_kernel<<<gridF, 256, 0, stream>>>(qT, kT, vB, Op, Lg);
    out_kernel<<<grid, 512, 0, stream>>>(Op, Lg, Wb + 3 * 16384, bo, gamma, x, y);
}